// Round 10
// baseline (308.884 us; speedup 1.0000x reference)
//
#include <hip/hip_runtime.h>
#include <hip/hip_bf16.h>

// Problem constants
#define BB   2
#define SS   2048
#define HH   2048
#define NH   32
#define NKV  8
#define HD   64
#define NTOK (BB * SS)          // 4096
#define NQKV (NH * HD + 2 * NKV * HD)  // 3072
#define KOFF (NH * HD)          // 2048 (start of K cols)
#define VOFF (NH * HD + NKV * HD)      // 2560 (start of V cols)

// Q pre-scale: 1/sqrt(HD) * log2(e), so attn can use exp2 directly
#define QSC  0.1803368801111244f

typedef short  short8  __attribute__((ext_vector_type(8)));
typedef short  short4v __attribute__((ext_vector_type(4)));
typedef float  float4v __attribute__((ext_vector_type(4)));

using bf16 = __hip_bfloat16;

#define DEV static __device__ __forceinline__

DEV short8 load8(const bf16* p) { return *(const short8*)p; }
DEV short8 load8s(const short* p) { return *(const short8*)p; }

DEV short f2bfbits(float f) {
    union { bf16 h; short s; } u;
    u.h = __float2bfloat16(f);
    return u.s;
}

DEV unsigned int packbf2(float a, float b) {
    return (unsigned int)(unsigned short)f2bfbits(a)
         | ((unsigned int)(unsigned short)f2bfbits(b) << 16);
}

// async global->LDS, 16B per lane. ldsptr must be wave-uniform; HW writes
// lane l's 16 bytes at ldsptr + l*16.
DEV void async16(const bf16* g, short* l) {
    __builtin_amdgcn_global_load_lds(
        (const __attribute__((address_space(1))) unsigned int*)g,
        (__attribute__((address_space(3))) unsigned int*)l, 16, 0, 0);
}

// ---------------- fp32 -> bf16 convert, all tensors in ONE launch ----------
__global__ __launch_bounds__(256) void cvt_all_kernel(
    const float* __restrict__ hidden, const float* __restrict__ q_w,
    const float* __restrict__ k_w, const float* __restrict__ v_w,
    const float* __restrict__ o_w,
    bf16* __restrict__ Hb, bf16* __restrict__ Wqkv, bf16* __restrict__ Wo) {
    int blk = blockIdx.x;
    const float* src;
    bf16* dst;
    int off;
    if (blk < 8192)       { src = hidden; dst = Hb;   off = blk * 1024; }
    else if (blk < 12288) { src = q_w; dst = Wqkv;    off = (blk - 8192) * 1024; }
    else if (blk < 13312) { src = k_w; dst = Wqkv + (size_t)KOFF * HH; off = (blk - 12288) * 1024; }
    else if (blk < 14336) { src = v_w; dst = Wqkv + (size_t)VOFF * HH; off = (blk - 13312) * 1024; }
    else                  { src = o_w; dst = Wo;      off = (blk - 14336) * 1024; }
    int i = off + threadIdx.x * 4;
    float4 v = *(const float4*)(src + i);
    short4v o;
    o[0] = f2bfbits(v.x); o[1] = f2bfbits(v.y);
    o[2] = f2bfbits(v.z); o[3] = f2bfbits(v.w);
    *(short4v*)(dst + i) = o;
}
#define CVT_BLOCKS 18432

// ---------------- 128x128 GEMM mainloop, BK=64, XOR-swizzled LDS ----------
// (unchanged from r9: 74 us qkv, MfmaUtil 29%, 0 bank conflicts — near this
// structure's plateau for K=2048; m99/m100/m131-141 say source-level
// pipelining on this structure is neutral, so leave it.)
struct GemmCtx {
    const bf16 *gA, *gB;
    short *lA, *lB;
    const short *rdA, *rdB;
    int p0;
};

DEV void gemm_setup(GemmCtx& c, const bf16* A, const bf16* Bw, int K,
                    int m0, int n0, short* As, short* Bs) {
    int lane = threadIdx.x & 63, w = threadIdx.x >> 6;
    int quad = lane >> 4, tq = lane & 15;
    int srow = lane >> 3;                  // 0..7
    int schunk = (lane & 7) ^ srow;        // swizzled 16B-chunk index
    c.gA = A  + (size_t)(m0 + w * 32 + srow) * K + schunk * 8;
    c.gB = Bw + (size_t)(n0 + w * 32 + srow) * K + schunk * 8;
    c.lA = As + (w * 32) * 64;
    c.lB = Bs + (w * 32) * 64;
    int mbase = (w >> 1) * 64, nbase = (w & 1) * 64;
    c.rdA = As + (mbase + tq) * 64;
    c.rdB = Bs + (nbase + tq) * 64;
    c.p0 = (quad ^ (tq & 7)) * 8;
}

DEV void gemm_mainloop(GemmCtx& c, int K, float4v acc[4][4]) {
    for (int k0 = 0; k0 < K; k0 += 64) {
        __syncthreads();                     // prev reads done
#pragma unroll
        for (int cc = 0; cc < 4; ++cc) {
            async16(c.gA + (size_t)cc * 8 * K + k0, c.lA + cc * 8 * 64);
            async16(c.gB + (size_t)cc * 8 * K + k0, c.lB + cc * 8 * 64);
        }
        __syncthreads();                     // vmcnt drain: 32 KB staged
#pragma unroll
        for (int kh = 0; kh < 2; ++kh) {
            int off = c.p0 ^ (kh * 32);      // XOR, not add (swizzle)
            short8 af[4], bfr[4];
#pragma unroll
            for (int mi = 0; mi < 4; ++mi) af[mi]  = load8s(c.rdA + mi * 16 * 64 + off);
#pragma unroll
            for (int nj = 0; nj < 4; ++nj) bfr[nj] = load8s(c.rdB + nj * 16 * 64 + off);
#pragma unroll
            for (int mi = 0; mi < 4; ++mi)
#pragma unroll
                for (int nj = 0; nj < 4; ++nj)
                    acc[mi][nj] = __builtin_amdgcn_mfma_f32_16x16x32_bf16(
                        af[mi], bfr[nj], acc[mi][nj], 0, 0, 0);
        }
    }
}

// ---------------- QKV projection + bias + RoPE ----------------
__global__ __launch_bounds__(256, 3) void qkv_kernel(
    const bf16* __restrict__ Hb, const bf16* __restrict__ Wqkv,
    const float* __restrict__ qbias, const float* __restrict__ kbias,
    const float* __restrict__ vbias,
    const float* __restrict__ cosp, const float* __restrict__ sinp,
    const int* __restrict__ posp,
    bf16* __restrict__ Qb, bf16* __restrict__ Kb, bf16* __restrict__ Vt) {
    __shared__ __align__(16) short As[128 * 64];
    __shared__ __align__(16) short Bs[128 * 64];
    int lane = threadIdx.x & 63, w = threadIdx.x >> 6;
    int quad = lane >> 4, tq = lane & 15;
    int m0 = blockIdx.y * 128, n0 = blockIdx.x * 128;
    int mbase = (w >> 1) * 64, nbase = (w & 1) * 64;

    GemmCtx c;
    gemm_setup(c, Hb, Wqkv, HH, m0, n0, As, Bs);
    float4v acc[4][4] = {};
    gemm_mainloop(c, HH, acc);

    float biasv[4];
#pragma unroll
    for (int nj = 0; nj < 4; ++nj) {
        int colg = n0 + nbase + nj * 16 + tq;
        biasv[nj] = (colg < KOFF) ? qbias[colg]
                  : (colg < VOFF) ? kbias[colg - KOFF] : vbias[colg - VOFF];
    }

#pragma unroll
    for (int mi = 0; mi < 4; ++mi) {
#pragma unroll
        for (int r = 0; r < 4; ++r) {
            int tok = m0 + mbase + mi * 16 + quad * 4 + r;
            int p = posp[tok];
#pragma unroll
            for (int nj = 0; nj < 4; ++nj) {
                int colg = n0 + nbase + nj * 16 + tq;
                float val = acc[mi][nj][r] + biasv[nj];
                if (colg < VOFF) {
                    float pv = __shfl_xor(val, 1);
                    int jh = colg & 63;
                    float Cv = cosp[p * 32 + (jh & 31)];
                    float Sv = sinp[p * 32 + (jh & 31)];
                    float outv = (jh & 1) ? (val * Cv + pv * Sv)
                                          : (val * Cv - pv * Sv);
                    if (colg < KOFF)
                        // Q pre-scaled by 1/sqrt(HD)*log2e for exp2-softmax
                        Qb[(size_t)tok * (NH * HD) + colg] = __float2bfloat16(outv * QSC);
                    else
                        Kb[(size_t)tok * (NKV * HD) + (colg - KOFF)] = __float2bfloat16(outv);
                } else {
                    int c2 = colg - VOFF;
                    int kv = c2 >> 6, d = c2 & 63;
                    int bb = tok >> 11, s = tok & (SS - 1);
                    Vt[(((size_t)bb * NKV + kv) * HD + d) * SS + s] = __float2bfloat16(val);
                }
            }
        }
    }
}

// ---------------- output projection ----------------
__global__ __launch_bounds__(256, 3) void oproj_kernel(
    const bf16* __restrict__ AO, const bf16* __restrict__ Wo,
    float* __restrict__ out) {
    __shared__ __align__(16) short As[128 * 64];
    __shared__ __align__(16) short Bs[128 * 64];
    int lane = threadIdx.x & 63, w = threadIdx.x >> 6;
    int quad = lane >> 4, tq = lane & 15;
    int m0 = blockIdx.y * 128, n0 = blockIdx.x * 128;
    int mbase = (w >> 1) * 64, nbase = (w & 1) * 64;

    GemmCtx c;
    gemm_setup(c, AO, Wo, NH * HD, m0, n0, As, Bs);
    float4v acc[4][4] = {};
    gemm_mainloop(c, NH * HD, acc);

#pragma unroll
    for (int mi = 0; mi < 4; ++mi) {
#pragma unroll
        for (int nj = 0; nj < 4; ++nj) {
            int colg = n0 + nbase + nj * 16 + tq;
#pragma unroll
            for (int r = 0; r < 4; ++r) {
                int tok = m0 + mbase + mi * 16 + quad * 4 + r;
                out[(size_t)tok * HH + colg] = acc[mi][nj][r];
            }
        }
    }
}

// ---------------- flash attention v8: double-buffered single-barrier -------
// v7 (32 q-rows/wave, cooperative XOR-swizzled staging) restructured into a
// 2-stage pipeline: ONE barrier per kv-step; at the barrier, the DMA issued
// one step earlier (into the alternate K/V buffer) has had a full compute
// phase (~32 MFMA + softmax) to land -> vmcnt drain ~free, barrier count
// halves. Masking is a wave-uniform runtime branch (only diagonal steps pay).
// LDS: 2x16 KB K/V + 18.4 KB P = 50.4 KB -> 2 blocks/CU at (256,2);
// grid 512 = exactly co-resident.
#define PST 72   // P-tile LDS row stride in shorts

DEV void attn_stage(int kv0, int w, int srow, int schunk,
                    const bf16* __restrict__ Kg, const bf16* __restrict__ Vg,
                    short* Ks, short* Vs) {
#pragma unroll
    for (int cc = 0; cc < 2; ++cc) {
        int rl = w * 16 + cc * 8;               // wave-uniform row base
        async16(Kg + (size_t)(kv0 + rl + srow) * (NKV * HD) + schunk * 8,
                Ks + rl * 64);
        async16(Vg + (size_t)(rl + srow) * SS + kv0 + schunk * 8,
                Vs + rl * 64);
    }
}

DEV void attn_compute(bool domask, int kv0, int qw0, int qw1, int quad, int tq,
                      const short* Ks, const short* Vs, short* myp,
                      const short8 (&aq)[2][2], float4v (&ot)[4][2], float (&ls)[2]) {
    int p0 = (quad ^ (tq & 7)) * 8;             // physical chunk offset

    // ---- scores S^T for both q-chunks; exp+pack per t to cap live regs ----
#pragma unroll
    for (int t = 0; t < 4; ++t) {
        const short* kr = Ks + (t * 16 + tq) * 64;
        short8 k0 = load8s(kr + p0);
        short8 k1 = load8s(kr + (p0 ^ 32));
        float4v s0 = {0.f, 0.f, 0.f, 0.f};
        float4v s1 = {0.f, 0.f, 0.f, 0.f};
        s0 = __builtin_amdgcn_mfma_f32_16x16x32_bf16(k0, aq[0][0], s0, 0, 0, 0);
        s0 = __builtin_amdgcn_mfma_f32_16x16x32_bf16(k1, aq[0][1], s0, 0, 0, 0);
        s1 = __builtin_amdgcn_mfma_f32_16x16x32_bf16(k0, aq[1][0], s1, 0, 0, 0);
        s1 = __builtin_amdgcn_mfma_f32_16x16x32_bf16(k1, aq[1][1], s1, 0, 0, 0);
#pragma unroll
        for (int qc = 0; qc < 2; ++qc) {
            const float4v& s = qc ? s1 : s0;
            int qw = qc ? qw1 : qw0;
            float p[4];
#pragma unroll
            for (int r = 0; r < 4; ++r) {
                float e = __builtin_amdgcn_exp2f(s[r]);
                if (domask) {                      // wave-uniform branch
                    int kvg = kv0 + t * 16 + quad * 4 + r;
                    e = (kvg <= qw) ? e : 0.f;
                }
                p[r] = e;
                ls[qc] += e;
            }
            int pos = (qc * 16 + tq) * PST + t * 16 + quad * 4;
            *(unsigned int*)(myp + pos)     = packbf2(p[0], p[1]);
            *(unsigned int*)(myp + pos + 2) = packbf2(p[2], p[3]);
        }
    }

    // ---- read P B-frags (same-wave RAW; in-order DS pipe) ----
    short8 pf00 = load8s(myp + tq * PST + quad * 8);
    short8 pf01 = load8s(myp + tq * PST + 32 + quad * 8);
    short8 pf10 = load8s(myp + (16 + tq) * PST + quad * 8);
    short8 pf11 = load8s(myp + (16 + tq) * PST + 32 + quad * 8);

    // ---- PV: O^T[d][q] += V^T[d][kv] * P[q][kv], both q-chunks ----
#pragma unroll
    for (int i = 0; i < 4; ++i) {
        const short* vr = Vs + (i * 16 + tq) * 64;
        short8 bv0 = load8s(vr + p0);
        short8 bv1 = load8s(vr + (p0 ^ 32));
        ot[i][0] = __builtin_amdgcn_mfma_f32_16x16x32_bf16(bv0, pf00, ot[i][0], 0, 0, 0);
        ot[i][0] = __builtin_amdgcn_mfma_f32_16x16x32_bf16(bv1, pf01, ot[i][0], 0, 0, 0);
        ot[i][1] = __builtin_amdgcn_mfma_f32_16x16x32_bf16(bv0, pf10, ot[i][1], 0, 0, 0);
        ot[i][1] = __builtin_amdgcn_mfma_f32_16x16x32_bf16(bv1, pf11, ot[i][1], 0, 0, 0);
    }
}

DEV void attn_superblock(int sb, int b, int h, int w, int lane, int quad, int tq,
                         const bf16* __restrict__ Qb,
                         const bf16* __restrict__ Kg, const bf16* __restrict__ Vg,
                         short* Ks0, short* Vs0, short* Ks1, short* Vs1,
                         short* myp, bf16* __restrict__ AO) {
    // wave w owns q rows sb + w*32 .. +31, as two 16-row chunks
    int qw0 = sb + w * 32 + tq;
    int qw1 = qw0 + 16;
    const bf16* Qr0 = Qb + (size_t)(b * SS + qw0) * (NH * HD) + h * HD + quad * 8;
    const bf16* Qr1 = Qr0 + (size_t)16 * (NH * HD);
    short8 aq[2][2];
    aq[0][0] = load8(Qr0); aq[0][1] = load8(Qr0 + 32);
    aq[1][0] = load8(Qr1); aq[1][1] = load8(Qr1 + 32);

    float4v ot[4][2] = {};
    float ls[2] = {0.f, 0.f};

    int srow = lane >> 3;                       // staging row within 8-row group
    int schunk = (lane & 7) ^ srow;             // swizzled 16B-chunk index
    int wrow = sb + w * 32;                     // wave's min q row
    int nsteps = sb / 64 + 2;                   // kv tiles 0 .. sb+64

    __syncthreads();                            // protect buf0 vs prior reads
    attn_stage(0, w, srow, schunk, Kg, Vg, Ks0, Vs0);

    for (int i = 0; i < nsteps; ++i) {
        int kv0 = i * 64;
        __syncthreads();    // drains DMA for buf[i&1]; prior reads of buf[(i+1)&1] done
        if (i + 1 < nsteps) {
            if ((i + 1) & 1) attn_stage(kv0 + 64, w, srow, schunk, Kg, Vg, Ks1, Vs1);
            else             attn_stage(kv0 + 64, w, srow, schunk, Kg, Vg, Ks0, Vs0);
        }
        bool domask = (kv0 + 63 > wrow);
        if (i & 1) attn_compute(domask, kv0, qw0, qw1, quad, tq, Ks1, Vs1, myp, aq, ot, ls);
        else       attn_compute(domask, kv0, qw0, qw1, quad, tq, Ks0, Vs0, myp, aq, ot, ls);
    }

#pragma unroll
    for (int qc = 0; qc < 2; ++qc) {
        float lsum = ls[qc];
        lsum += __shfl_xor(lsum, 16);
        lsum += __shfl_xor(lsum, 32);
        float inv = 1.0f / lsum;
        int qg = qc ? qw1 : qw0;
        bf16* obase = AO + (size_t)(b * SS + qg) * (NH * HD) + h * HD + quad * 4;
#pragma unroll
        for (int i = 0; i < 4; ++i) {
            short4v o;
#pragma unroll
            for (int r = 0; r < 4; ++r) o[r] = f2bfbits(ot[i][qc][r] * inv);
            *(short4v*)(obase + i * 16) = o;
        }
    }
}

// grid = (64, 8), block = 256. Block processes 128-row q-superblocks
// hi=(15-jq)*128 and lo=jq*128 sequentially -> uniform 34 kv-steps.
__global__ __launch_bounds__(256, 2) void attn_kernel(
    const bf16* __restrict__ Qb, const bf16* __restrict__ Kb,
    const bf16* __restrict__ Vt, bf16* __restrict__ AO) {
    __shared__ __align__(16) short Ks0[64 * 64];
    __shared__ __align__(16) short Vs0[64 * 64];
    __shared__ __align__(16) short Ks1[64 * 64];
    __shared__ __align__(16) short Vs1[64 * 64];
    __shared__ __align__(16) short plds[4][32 * PST];

    int lane = threadIdx.x & 63, w = threadIdx.x >> 6;
    int quad = lane >> 4, tq = lane & 15;

    // XCD-aware swizzle (gridDim.x=64, XCD = flat%8 = blockIdx.x&7):
    // each XCD sees 2 (b,kvh) pairs -> ~1 MB K/V per 4 MB L2.
    int x = blockIdx.x;
    int xcd = x & 7, xi = x >> 3;
    int pair = xcd * 2 + (xi & 1);
    int b = pair >> 3, kvh = pair & 7;
    int h = kvh * 4 + (xi >> 1);

    const bf16* Kg = Kb + (size_t)(b * SS) * (NKV * HD) + kvh * HD;
    const bf16* Vg = Vt + (size_t)((b * NKV + kvh) * HD) * SS;
    short* myp = &plds[w][0];

    int jq = blockIdx.y;                 // 0..7
    attn_superblock((15 - jq) * 128, b, h, w, lane, quad, tq, Qb, Kg, Vg,
                    Ks0, Vs0, Ks1, Vs1, myp, AO);
    attn_superblock(jq * 128,        b, h, w, lane, quad, tq, Qb, Kg, Vg,
                    Ks0, Vs0, Ks1, Vs1, myp, AO);
}

extern "C" void kernel_launch(void* const* d_in, const int* in_sizes, int n_in,
                              void* d_out, int out_size, void* d_ws, size_t ws_size,
                              hipStream_t stream) {
    const float* hidden = (const float*)d_in[0];
    const float* cosp   = (const float*)d_in[1];
    const float* sinp   = (const float*)d_in[2];
    const int*   posp   = (const int*)d_in[3];
    // d_in[4] = mask (unused; causal mask applied analytically)
    const float* q_w = (const float*)d_in[5];
    const float* q_b = (const float*)d_in[6];
    const float* k_w = (const float*)d_in[7];
    const float* k_b = (const float*)d_in[8];
    const float* v_w = (const float*)d_in[9];
    const float* v_b = (const float*)d_in[10];
    const float* o_w = (const float*)d_in[11];
    float* out = (float*)d_out;

    char* ws = (char*)d_ws;
    bf16* Hb   = (bf16*)ws; ws += (size_t)NTOK * HH * 2;          // 16 MiB
    bf16* Wqkv = (bf16*)ws; ws += (size_t)NQKV * HH * 2;          // 12 MiB
    bf16* Wo   = (bf16*)ws; ws += (size_t)HH * (NH * HD) * 2;     // 8 MiB
    bf16* Qb   = (bf16*)ws; ws += (size_t)NTOK * (NH * HD) * 2;   // 16 MiB
    bf16* Kb   = (bf16*)ws; ws += (size_t)NTOK * (NKV * HD) * 2;  // 4 MiB
    bf16* Vt   = (bf16*)ws; ws += (size_t)NTOK * (NKV * HD) * 2;  // 4 MiB
    bf16* AO   = (bf16*)ws; ws += (size_t)NTOK * (NH * HD) * 2;   // 16 MiB

    // 1) all fp32->bf16 conversions in a single launch
    cvt_all_kernel<<<CVT_BLOCKS, 256, 0, stream>>>(
        hidden, q_w, k_w, v_w, o_w, Hb, Wqkv, Wo);

    // 2) fused QKV GEMM + bias + RoPE (+ V transpose)
    qkv_kernel<<<dim3(NQKV / 128, NTOK / 128), 256, 0, stream>>>(
        Hb, Wqkv, q_b, k_b, v_b, cosp, sinp, posp, Qb, Kb, Vt);

    // 3) flash attention (causal, GQA 4:1)
    attn_kernel<<<dim3(64, 8), 256, 0, stream>>>(Qb, Kb, Vt, AO);

    // 4) output projection -> fp32 out
    oproj_kernel<<<dim3(HH / 128, NTOK / 128), 256, 0, stream>>>(AO, Wo, out);
}